// Round 9
// baseline (11631.967 us; speedup 1.0000x reference)
//
#include <hip/hip_runtime.h>

// PredictorRNN: 2076 sequential GRU steps in ONE persistent kernel.
// Round-9: sentinel-per-producer sync (one 64B line per group), untagged bf16
// h exchange via relaxed agent-scope (MALL-coherent) atomics; producer drains
// stores with __syncthreads (compiler emits s_waitcnt vmcnt(0) before
// s_barrier) then publishes a step sentinel. 512-thr blocks (8 waves);
// 16 groups x 4 blocks; h-stores coalesced via LDS transpose slab.

typedef __attribute__((ext_vector_type(8))) short short8;   // 8 x bf16 frag
typedef __attribute__((ext_vector_type(4))) float floatx4;

#define B_    256
#define T_    256
#define I_    64
#define H_    512
#define HZ    8
#define GBLK  4              // blocks per group
#define LPAD  520            // LDS h-staging pitch (ushorts)
#define SLABP 132            // transpose slab pitch (ushorts), 8B-divisible

#define MFMA_BF16(acc, a, b) \
  acc = __builtin_amdgcn_mfma_f32_16x16x32_bf16((a), (b), (acc), 0, 0, 0)

__device__ __forceinline__ float bf2f(unsigned short u) {
  union { unsigned int i; float f; } v; v.i = ((unsigned int)u) << 16; return v.f;
}
__device__ __forceinline__ unsigned short f2bf(float f) {
  union { float f; unsigned int i; } v; v.f = f;
  return (unsigned short)((v.i + 0x7FFFu + ((v.i >> 16) & 1u)) >> 16);  // RNE
}
__device__ __forceinline__ short8 ld8_f32_to_bf16(const float* p) {
  short8 r;
#pragma unroll
  for (int e = 0; e < 8; ++e) r[e] = (short)f2bf(p[e]);
  return r;
}
__device__ __forceinline__ float sigm(float xx) {
  return __builtin_amdgcn_rcpf(1.f + __expf(-xx));
}
__device__ __forceinline__ float tanh_fast(float xx) {
  float e = __expf(2.f * xx);                 // +inf -> 1, 0 -> -1
  return 1.f - 2.f * __builtin_amdgcn_rcpf(e + 1.f);
}
// relaxed agent-scope atomics: L1/L2-bypass, coherent at MALL. No fences.
__device__ __forceinline__ unsigned long long ald64(const void* p) {
  return __hip_atomic_load((const unsigned long long*)p, __ATOMIC_RELAXED,
                           __HIP_MEMORY_SCOPE_AGENT);
}
__device__ __forceinline__ void ast64(void* p, unsigned long long v) {
  __hip_atomic_store((unsigned long long*)p, v, __ATOMIC_RELAXED,
                     __HIP_MEMORY_SCOPE_AGENT);
}
__device__ __forceinline__ void ast32(unsigned int* p, unsigned int v) {
  __hip_atomic_store(p, v, __ATOMIC_RELAXED, __HIP_MEMORY_SCOPE_AGENT);
}
__device__ __forceinline__ void ast16(unsigned short* p, unsigned short v) {
  __hip_atomic_store(p, v, __ATOMIC_RELAXED, __HIP_MEMORY_SCOPE_AGENT);
}

extern "C" __global__ void __launch_bounds__(512, 2)
gru_chain(const float* __restrict__ x,       // [256][256][64] fp32
          const float* __restrict__ w_ih,    // [1536][64]   fp32
          const float* __restrict__ w_hh,    // [1536][512]  fp32
          const float* __restrict__ b_ih,    // [1536]       fp32
          const float* __restrict__ b_hh,    // [1536]       fp32
          const float* __restrict__ fc_w,    // [64][512]    fp32
          const float* __restrict__ fc_b,    // [64]         fp32
          float* __restrict__ out,           // [256][8][64] fp32
          unsigned short* __restrict__ hbuf, // ws: [2][256][512] bf16 (MALL)
          unsigned short* __restrict__ xext, // ws: [8][256][64]  bf16 (MALL)
          unsigned int* __restrict__ sent,   // ws: [16][16] (one 64B line/group)
          unsigned int* __restrict__ psent)  // ws: [16][16]
{
  const int tid  = threadIdx.x;
  const int wave = tid >> 6;                  // 0..7
  const int lane = tid & 63;
  const int bx   = blockIdx.x;                // 0..63
  const int grp  = bx & 15;                   // 16 groups x 4 blocks
  const int pb   = bx >> 4;                   // producer index in group, 0..3
  const int ju   = (pb << 3) | wave;          // 0..31 j-tile unit in group
  const int n16  = lane & 15;
  const int quad = lane >> 4;
  const int jg   = ju * 16 + n16;             // output column j (0..511)
  const int rowbase = grp * 16;               // 16 batch rows per group
  const int jblk = pb * 128;                  // block's 128-col stripe

  __shared__ __align__(16) unsigned short hls[16 * LPAD];   // h staging
  __shared__ __align__(16) unsigned short slab[16 * SLABP]; // transpose slab

  // ---- one-time: fp32 weights -> bf16 B-fragments in registers ----
  // B-frag (16x16x32): lane holds B[k = kc*32 + quad*8 + e][n = lane&15];
  // B[k][j] = W[j][k] => weight row (gate*512+jg), cols kc*32+quad*8.
  short8 wR[18], wZ[18], wHN[16], wXN[2];
  {
    const int koff = quad * 8;
    const float* whr = w_hh + (size_t)(0 * H_ + jg) * H_ + koff;
    const float* whz = w_hh + (size_t)(1 * H_ + jg) * H_ + koff;
    const float* whn = w_hh + (size_t)(2 * H_ + jg) * H_ + koff;
#pragma unroll
    for (int kc = 0; kc < 16; ++kc) {
      wR[kc]  = ld8_f32_to_bf16(whr + kc * 32);
      wZ[kc]  = ld8_f32_to_bf16(whz + kc * 32);
      wHN[kc] = ld8_f32_to_bf16(whn + kc * 32);
    }
    const float* wir = w_ih + (size_t)(0 * H_ + jg) * I_ + koff;
    const float* wiz = w_ih + (size_t)(1 * H_ + jg) * I_ + koff;
    const float* win = w_ih + (size_t)(2 * H_ + jg) * I_ + koff;
#pragma unroll
    for (int kc = 0; kc < 2; ++kc) {
      wR[16 + kc] = ld8_f32_to_bf16(wir + kc * 32);
      wZ[16 + kc] = ld8_f32_to_bf16(wiz + kc * 32);
      wXN[kc]     = ld8_f32_to_bf16(win + kc * 32);
    }
  }
  const float brc = b_ih[jg]          + b_hh[jg];
  const float bzc = b_ih[H_ + jg]     + b_hh[H_ + jg];
  const float bxn = b_ih[2 * H_ + jg];
  const float bhn = b_hh[2 * H_ + jg];

  float hloc[4] = {0.f, 0.f, 0.f, 0.f};   // fp32 recurrent carry (C/D layout)
  unsigned int* gs = sent  + grp * 16;    // this group's sentinel line
  unsigned int* ps = psent + grp * 16;

  int s = 0;
  for (int p = 0; p < HZ; ++p) {
    const int Tp = T_ + p;
    for (int t = 0; t < Tp; ++t) {
      // ---- x A-fragment (prefetch overlaps the sentinel spin) ----
      short8 xaf0, xaf1;
      if (t < T_) {
        const float* xs = x + ((size_t)(rowbase + n16) * T_ + t) * I_ + quad * 8;
        xaf0 = ld8_f32_to_bf16(xs);
        xaf1 = ld8_f32_to_bf16(xs + 32);
      }
      // ---- wait: all 4 producers published step s-1 (sentinel >= s) ----
      if (s > 0) {
        const unsigned int want = (unsigned int)s;
        for (;;) {
          unsigned long long q0 = ald64(gs);      // words 0,1
          unsigned long long q1 = ald64(gs + 2);  // words 2,3
          if ((unsigned int)q0 >= want && (unsigned int)(q0 >> 32) >= want &&
              (unsigned int)q1 >= want && (unsigned int)(q1 >> 32) >= want)
            break;
          __builtin_amdgcn_s_sleep(1);
        }
        asm volatile("" ::: "memory");
      }
      if (t >= T_) {   // appended timestep: gated by pass sentinel
        const int p2 = t - T_;
        const unsigned int want = (unsigned int)(p2 + 1);
        for (;;) {
          unsigned long long q0 = ald64(ps);
          unsigned long long q1 = ald64(ps + 2);
          if ((unsigned int)q0 >= want && (unsigned int)(q0 >> 32) >= want &&
              (unsigned int)q1 >= want && (unsigned int)(q1 >> 32) >= want)
            break;
          __builtin_amdgcn_s_sleep(1);
        }
        asm volatile("" ::: "memory");
        const unsigned short* xb =
            xext + ((size_t)p2 * B_ + rowbase + n16) * I_ + quad * 8;
        unsigned long long u0 = ald64(xb),      u1 = ald64(xb + 4);
        unsigned long long u2 = ald64(xb + 32), u3 = ald64(xb + 36);
        union { unsigned long long q[2]; short8 v; } c0, c1;
        c0.q[0] = u0; c0.q[1] = u1; c1.q[0] = u2; c1.q[1] = u3;
        xaf0 = c0.v; xaf1 = c1.v;
      }
      // ---- bulk-stage h^(s-1) (parity (s+1)&1) into LDS: 16KB, 4 x 8B/thr ----
      if (s > 0) {
        const unsigned short* hb = hbuf + (size_t)((s + 1) & 1) * (B_ * H_) +
                                   (size_t)rowbase * H_;
#pragma unroll
        for (int i = 0; i < 4; ++i) {
          int f = tid + (i << 9);          // 0..2047 (8B chunks)
          int r = f >> 7;                  // 128 chunks per 512-col row
          int o = (f & 127) << 2;          // ushort offset
          unsigned long long q = ald64(hb + (size_t)r * H_ + o);
          *(unsigned long long*)&hls[r * LPAD + o] = q;
        }
      } else {
#pragma unroll
        for (int i = 0; i < 4; ++i) {
          int f = tid + (i << 9);
          int r = f >> 7, o = (f & 127) << 2;
          *(unsigned long long*)&hls[r * LPAD + o] = 0ull;
        }
      }
      __syncthreads();   // staging visible to all waves
      short8 haf[16];
#pragma unroll
      for (int kc = 0; kc < 16; ++kc)
        haf[kc] = *(const short8*)&hls[n16 * LPAD + kc * 32 + quad * 8];

      floatx4 aR = {0.f, 0.f, 0.f, 0.f};
      floatx4 aZ = {0.f, 0.f, 0.f, 0.f};
      floatx4 aN = {0.f, 0.f, 0.f, 0.f};
      floatx4 aX = {0.f, 0.f, 0.f, 0.f};
#pragma unroll
      for (int kc = 0; kc < 16; ++kc) {
        MFMA_BF16(aR, haf[kc], wR[kc]);
        MFMA_BF16(aZ, haf[kc], wZ[kc]);
        MFMA_BF16(aN, haf[kc], wHN[kc]);
      }
      MFMA_BF16(aR, xaf0, wR[16]);  MFMA_BF16(aR, xaf1, wR[17]);
      MFMA_BF16(aZ, xaf0, wZ[16]);  MFMA_BF16(aZ, xaf1, wZ[17]);
      MFMA_BF16(aX, xaf0, wXN[0]);  MFMA_BF16(aX, xaf1, wXN[1]);

      // ---- epilogue: gates -> transpose slab (block-local 16x128 stripe) ----
#pragma unroll
      for (int i = 0; i < 4; ++i) {
        float rv = sigm(aR[i] + brc);
        float zv = sigm(aZ[i] + bzc);
        float nv = tanh_fast(aX[i] + bxn + rv * (aN[i] + bhn));
        float hn = (1.f - zv) * nv + zv * hloc[i];
        hloc[i]  = hn;
        slab[(quad * 4 + i) * SLABP + wave * 16 + n16] = f2bf(hn);
      }
      __syncthreads();   // slab complete; also separates hls reads from reuse
      {   // coalesced bypass store: 8B/thread, 64B-line aligned
        const int r = tid >> 5;            // 16 rows, 32 threads each
        const int o = (tid & 31) << 2;     // ushort offset in 128-col stripe
        unsigned long long q = *(const unsigned long long*)&slab[r * SLABP + o];
        ast64(hbuf + (size_t)(s & 1) * (B_ * H_) +
              (size_t)(rowbase + r) * H_ + jblk + o, q);
      }
      __syncthreads();   // compiler emits s_waitcnt vmcnt(0) before s_barrier:
                         // all 8 waves' stores are at MALL before the sentinel
      if (tid == 0) ast32(&gs[pb], (unsigned int)(s + 1));
      ++s;
    }
    // ---- pass boundary: pred_p = h_final @ fc_w^T + fc_b ----
    {
      const unsigned int want = (unsigned int)s;   // h^(s-1) published
      for (;;) {
        unsigned long long q0 = ald64(gs);
        unsigned long long q1 = ald64(gs + 2);
        if ((unsigned int)q0 >= want && (unsigned int)(q0 >> 32) >= want &&
            (unsigned int)q1 >= want && (unsigned int)(q1 >> 32) >= want)
          break;
        __builtin_amdgcn_s_sleep(1);
      }
      asm volatile("" ::: "memory");
      const unsigned short* hb = hbuf + (size_t)((s + 1) & 1) * (B_ * H_) +
                                 (size_t)rowbase * H_;
#pragma unroll
      for (int i = 0; i < 4; ++i) {
        int f = tid + (i << 9);
        int r = f >> 7, o = (f & 127) << 2;
        unsigned long long q = ald64(hb + (size_t)r * H_ + o);
        *(unsigned long long*)&hls[r * LPAD + o] = q;
      }
      __syncthreads();
      const int mm  = lane & 15;
      const int sub = lane >> 4;
#pragma unroll
      for (int cc = 0; cc < 2; ++cc) {
        const int c = ju * 2 + cc;
        const unsigned short* hrow = &hls[mm * LPAD + sub * 128];
        const float* wrow = fc_w + (size_t)c * H_ + sub * 128;
        float acc = 0.f;
#pragma unroll
        for (int kk = 0; kk < 128; kk += 8) {
          short8 hv = *(const short8*)(hrow + kk);
#pragma unroll
          for (int e = 0; e < 8; ++e)
            acc = fmaf(bf2f((unsigned short)hv[e]), wrow[kk + e], acc);
        }
        acc += __shfl_xor(acc, 16, 64);
        acc += __shfl_xor(acc, 32, 64);
        if (sub == 0) {
          float val = acc + fc_b[c];
          out[((size_t)(rowbase + mm) * HZ + p) * I_ + c] = val;   // fp32
          ast16(&xext[((size_t)p * B_ + rowbase + mm) * I_ + c], f2bf(val));
        }
      }
      __syncthreads();   // xext stores drained; hls reads done
      if (tid == 0) ast32(&ps[pb], (unsigned int)(p + 1));
    }
  }
}

extern "C" void kernel_launch(void* const* d_in, const int* in_sizes, int n_in,
                              void* d_out, int out_size, void* d_ws, size_t ws_size,
                              hipStream_t stream) {
  const float* x    = (const float*)d_in[0];
  const float* w_ih = (const float*)d_in[1];
  const float* w_hh = (const float*)d_in[2];
  const float* b_ih = (const float*)d_in[3];
  const float* b_hh = (const float*)d_in[4];
  const float* fc_w = (const float*)d_in[5];
  const float* fc_b = (const float*)d_in[6];
  float* out = (float*)d_out;

  unsigned char* ws = (unsigned char*)d_ws;
  const size_t hbuf_b = (size_t)2 * B_ * H_ * 2;   // 512 KiB bf16
  const size_t xext_b = (size_t)HZ * B_ * I_ * 2;  // 256 KiB bf16
  const size_t sen_b  = (size_t)16 * 16 * 4;       // 1 KiB (64B line/group)
  unsigned short* hbuf = (unsigned short*)ws;
  unsigned short* xext = (unsigned short*)(ws + hbuf_b);
  unsigned int* sent   = (unsigned int*)(ws + hbuf_b + xext_b);
  unsigned int* psent  = (unsigned int*)(ws + hbuf_b + xext_b + sen_b);

  // zero sentinels (0 = nothing published; 0xAA poison is overwritten here)
  hipMemsetAsync(d_ws, 0, hbuf_b + xext_b + 2 * sen_b, stream);

  // 64 blocks x 512 threads: 16 groups x 4 blocks, all co-resident
  gru_chain<<<dim3(64), dim3(512), 0, stream>>>(
      x, w_ih, w_hh, b_ih, b_hh, fc_w, fc_b, out, hbuf, xext, sent, psent);
}

// Round 10
// 6471.096 us; speedup vs baseline: 1.7975x; 1.7975x over previous
//
#include <hip/hip_runtime.h>

// PredictorRNN: 2076 sequential GRU steps in ONE persistent kernel.
// Round-10 = round-8 (champion, 6.5ms) + escalating poll backoff.
// TAGGED h-exchange: every h element stored as (step_tag<<16|bf16) u32 via
// relaxed agent-scope atomics (MALL-coherent). Consumers poll the data
// itself (detection == arrival; no flags, no fences, no inline asm).
// Poll retries back off 1->4->16 s_sleep units to kill fabric congestion.
// 128 blocks x 256 threads (4 waves => 512-VGPR budget; weights stay
// register-resident — 512-thread blocks cap at 256 VGPR and SPILL: round-9).

typedef __attribute__((ext_vector_type(8))) short short8;   // 8 x bf16 frag
typedef __attribute__((ext_vector_type(4))) float floatx4;

#define B_    256
#define T_    256
#define I_    64
#define H_    512
#define HZ    8
#define LPAD  520            // LDS staging pitch (ushorts), rows 16B-aligned
#define HLSZ  (16 * LPAD)    // one staging buffer (16 rows)

#define MFMA_BF16(acc, a, b) \
  acc = __builtin_amdgcn_mfma_f32_16x16x32_bf16((a), (b), (acc), 0, 0, 0)

// escalating backoff for MALL poll loops (it = retry count)
#define POLL_BACKOFF(it)                         \
  do {                                           \
    if ((it) < 2)      __builtin_amdgcn_s_sleep(1);  \
    else if ((it) < 8) __builtin_amdgcn_s_sleep(4);  \
    else               __builtin_amdgcn_s_sleep(16); \
  } while (0)

__device__ __forceinline__ float bf2f(unsigned short u) {
  union { unsigned int i; float f; } v; v.i = ((unsigned int)u) << 16; return v.f;
}
__device__ __forceinline__ unsigned short f2bf(float f) {
  union { float f; unsigned int i; } v; v.f = f;
  return (unsigned short)((v.i + 0x7FFFu + ((v.i >> 16) & 1u)) >> 16);  // RNE
}
__device__ __forceinline__ short8 ld8_f32_to_bf16(const float* p) {
  short8 r;
#pragma unroll
  for (int e = 0; e < 8; ++e) r[e] = (short)f2bf(p[e]);
  return r;
}
__device__ __forceinline__ float sigm(float xx) {
  return __builtin_amdgcn_rcpf(1.f + __expf(-xx));
}
__device__ __forceinline__ float tanh_fast(float xx) {
  float e = __expf(2.f * xx);                 // +inf -> 1, 0 -> -1
  return 1.f - 2.f * __builtin_amdgcn_rcpf(e + 1.f);
}
// relaxed agent-scope atomics (lower to global ops with L1/L2 bypass -> MALL)
__device__ __forceinline__ unsigned long long ald64(const unsigned int* p) {
  return __hip_atomic_load((const unsigned long long*)p, __ATOMIC_RELAXED,
                           __HIP_MEMORY_SCOPE_AGENT);
}
__device__ __forceinline__ void ast32(unsigned int* p, unsigned int v) {
  __hip_atomic_store(p, v, __ATOMIC_RELAXED, __HIP_MEMORY_SCOPE_AGENT);
}

extern "C" __global__ void __launch_bounds__(256, 1)
gru_chain(const float* __restrict__ x,       // [256][256][64] fp32
          const float* __restrict__ w_ih,    // [1536][64]   fp32
          const float* __restrict__ w_hh,    // [1536][512]  fp32
          const float* __restrict__ b_ih,    // [1536]       fp32
          const float* __restrict__ b_hh,    // [1536]       fp32
          const float* __restrict__ fc_w,    // [64][512]    fp32
          const float* __restrict__ fc_b,    // [64]         fp32
          float* __restrict__ out,           // [256][8][64] fp32
          unsigned int* __restrict__ hbuf,   // ws: [2][256][512] tagged u32
          unsigned int* __restrict__ xext)   // ws: [8][256][64]  tagged u32
{
  const int tid  = threadIdx.x;
  const int wave = tid >> 6;                  // 0..3
  const int lane = tid & 63;
  const int bx   = blockIdx.x;                // 0..127
  const int grp  = bx & 15;                   // 16 groups x 8 blocks
  const int ju   = ((bx >> 4) << 2) | wave;   // 0..31 j-tile unit in group
  const int n16  = lane & 15;
  const int quad = lane >> 4;
  const int jg   = ju * 16 + n16;             // output column j (0..511)
  const int rowbase = grp * 16;               // 16 batch rows per group

  __shared__ __align__(16) unsigned short hls[2 * HLSZ];  // double-buffered

  // ---- one-time: fp32 weights -> bf16 B-fragments in registers ----
  // B-frag (16x16x32): lane holds B[k = kc*32 + quad*8 + e][n = lane&15];
  // B[k][j] = W[j][k] => weight row (gate*512+jg), cols kc*32+quad*8.
  short8 wR[18], wZ[18], wHN[16], wXN[2];
  {
    const int koff = quad * 8;
    const float* whr = w_hh + (size_t)(0 * H_ + jg) * H_ + koff;
    const float* whz = w_hh + (size_t)(1 * H_ + jg) * H_ + koff;
    const float* whn = w_hh + (size_t)(2 * H_ + jg) * H_ + koff;
#pragma unroll
    for (int kc = 0; kc < 16; ++kc) {
      wR[kc]  = ld8_f32_to_bf16(whr + kc * 32);
      wZ[kc]  = ld8_f32_to_bf16(whz + kc * 32);
      wHN[kc] = ld8_f32_to_bf16(whn + kc * 32);
    }
    const float* wir = w_ih + (size_t)(0 * H_ + jg) * I_ + koff;
    const float* wiz = w_ih + (size_t)(1 * H_ + jg) * I_ + koff;
    const float* win = w_ih + (size_t)(2 * H_ + jg) * I_ + koff;
#pragma unroll
    for (int kc = 0; kc < 2; ++kc) {
      wR[16 + kc] = ld8_f32_to_bf16(wir + kc * 32);
      wZ[16 + kc] = ld8_f32_to_bf16(wiz + kc * 32);
      wXN[kc]     = ld8_f32_to_bf16(win + kc * 32);
    }
  }
  const float brc = b_ih[jg]          + b_hh[jg];
  const float bzc = b_ih[H_ + jg]     + b_hh[H_ + jg];
  const float bxn = b_ih[2 * H_ + jg];
  const float bhn = b_hh[2 * H_ + jg];

  float hloc[4] = {0.f, 0.f, 0.f, 0.f};   // fp32 recurrent carry (C/D layout)

  int s = 0;
  for (int p = 0; p < HZ; ++p) {
    const int Tp = T_ + p;
    for (int t = 0; t < Tp; ++t) {
      // ---- x A-fragment (prefetch overlaps the h spin) ----
      short8 xaf0, xaf1;
      if (t < T_) {
        const float* xs = x + ((size_t)(rowbase + n16) * T_ + t) * I_ + quad * 8;
        xaf0 = ld8_f32_to_bf16(xs);
        xaf1 = ld8_f32_to_bf16(xs + 32);
      }
      // ---- stage h^(s-1) (tagged, self-synchronizing) into LDS[s&1] ----
      unsigned short* hl = &hls[(s & 1) * HLSZ];
      if (s > 0) {
        const unsigned int want = (unsigned int)s;   // written at step s-1
        const unsigned int* hb = hbuf + (size_t)((s + 1) & 1) * (B_ * H_) +
                                 (size_t)rowbase * H_;
        unsigned long long v[16];
#pragma unroll
        for (int i = 0; i < 16; ++i) {
          int c = tid + (i << 8), r = c >> 8, o = (c & 255) << 1;
          v[i] = ald64(hb + (size_t)r * H_ + o);
        }
        int it = 0;
        for (;;) {
          bool all = true;
#pragma unroll
          for (int i = 0; i < 16; ++i) {
            unsigned int w0 = (unsigned int)v[i];
            unsigned int w1 = (unsigned int)(v[i] >> 32);
            if (((w0 >> 16) != want) || ((w1 >> 16) != want)) {
              all = false;
              int c = tid + (i << 8), r = c >> 8, o = (c & 255) << 1;
              v[i] = ald64(hb + (size_t)r * H_ + o);
            }
          }
          if (all) break;
          POLL_BACKOFF(it);
          ++it;
        }
#pragma unroll
        for (int i = 0; i < 16; ++i) {
          int c = tid + (i << 8), r = c >> 8, o = (c & 255) << 1;
          unsigned int w0 = (unsigned int)v[i];
          unsigned int w1 = (unsigned int)(v[i] >> 32);
          *(unsigned int*)&hl[r * LPAD + o] = (w0 & 0xffffu) | (w1 << 16);
        }
      } else {  // s == 0: h_prev = 0
#pragma unroll
        for (int i = 0; i < 16; ++i) {
          int c = tid + (i << 8), r = c >> 8, o = (c & 255) << 1;
          *(unsigned int*)&hl[r * LPAD + o] = 0u;
        }
      }
      // ---- xext A-fragment for appended timesteps (tagged) ----
      if (t >= T_) {
        const int p2 = t - T_;
        const unsigned int wantx = (unsigned int)(p2 + 1);
        const unsigned int* xb =
            xext + ((size_t)p2 * B_ + rowbase + n16) * I_;
        unsigned long long u[8];
#pragma unroll
        for (int k = 0; k < 8; ++k) {
          int off = (k < 4) ? (quad * 8 + 2 * k) : (32 + quad * 8 + 2 * (k - 4));
          u[k] = ald64(xb + off);
        }
        int it = 0;
        for (;;) {
          bool all = true;
#pragma unroll
          for (int k = 0; k < 8; ++k) {
            unsigned int w0 = (unsigned int)u[k];
            unsigned int w1 = (unsigned int)(u[k] >> 32);
            if (((w0 >> 16) != wantx) || ((w1 >> 16) != wantx)) {
              all = false;
              int off = (k < 4) ? (quad * 8 + 2 * k)
                                : (32 + quad * 8 + 2 * (k - 4));
              u[k] = ald64(xb + off);
            }
          }
          if (all) break;
          POLL_BACKOFF(it);
          ++it;
        }
#pragma unroll
        for (int k = 0; k < 4; ++k) {
          xaf0[2 * k]     = (short)(unsigned short)u[k];
          xaf0[2 * k + 1] = (short)(unsigned short)(u[k] >> 32);
          xaf1[2 * k]     = (short)(unsigned short)u[4 + k];
          xaf1[2 * k + 1] = (short)(unsigned short)(u[4 + k] >> 32);
        }
      }
      __syncthreads();   // staging visible; also protects LDS parity reuse
      short8 haf[16];
#pragma unroll
      for (int kc = 0; kc < 16; ++kc)
        haf[kc] = *(const short8*)&hl[n16 * LPAD + kc * 32 + quad * 8];

      floatx4 aR = {0.f, 0.f, 0.f, 0.f};
      floatx4 aZ = {0.f, 0.f, 0.f, 0.f};
      floatx4 aN = {0.f, 0.f, 0.f, 0.f};
      floatx4 aX = {0.f, 0.f, 0.f, 0.f};
#pragma unroll
      for (int kc = 0; kc < 16; ++kc) {
        MFMA_BF16(aR, haf[kc], wR[kc]);
        MFMA_BF16(aZ, haf[kc], wZ[kc]);
        MFMA_BF16(aN, haf[kc], wHN[kc]);
      }
      MFMA_BF16(aR, xaf0, wR[16]);  MFMA_BF16(aR, xaf1, wR[17]);
      MFMA_BF16(aZ, xaf0, wZ[16]);  MFMA_BF16(aZ, xaf1, wZ[17]);
      MFMA_BF16(aX, xaf0, wXN[0]);  MFMA_BF16(aX, xaf1, wXN[1]);

      // ---- epilogue: tagged scatter stores, fire-and-forget ----
      // (lanes n16=0..15 of a quad hit consecutive j -> 64B-line coalesced)
      unsigned int* hd = hbuf + (size_t)(s & 1) * (B_ * H_);
      const unsigned int tg = ((unsigned int)(s + 1)) << 16;
#pragma unroll
      for (int i = 0; i < 4; ++i) {
        float rv = sigm(aR[i] + brc);
        float zv = sigm(aZ[i] + bzc);
        float nv = tanh_fast(aX[i] + bxn + rv * (aN[i] + bhn));
        float hn = (1.f - zv) * nv + zv * hloc[i];
        hloc[i]  = hn;
        ast32(&hd[(size_t)(rowbase + quad * 4 + i) * H_ + jg],
              tg | (unsigned int)f2bf(hn));
      }
      ++s;
    }
    // ---- pass boundary: pred_p = h_final @ fc_w^T + fc_b ----
    {
      unsigned short* hl = &hls[(s & 1) * HLSZ];
      const unsigned int want = (unsigned int)s;   // tag of h^(s-1)
      const unsigned int* hb = hbuf + (size_t)((s + 1) & 1) * (B_ * H_) +
                               (size_t)rowbase * H_;
      unsigned long long v[16];
#pragma unroll
      for (int i = 0; i < 16; ++i) {
        int c = tid + (i << 8), r = c >> 8, o = (c & 255) << 1;
        v[i] = ald64(hb + (size_t)r * H_ + o);
      }
      int it = 0;
      for (;;) {
        bool all = true;
#pragma unroll
        for (int i = 0; i < 16; ++i) {
          unsigned int w0 = (unsigned int)v[i];
          unsigned int w1 = (unsigned int)(v[i] >> 32);
          if (((w0 >> 16) != want) || ((w1 >> 16) != want)) {
            all = false;
            int c = tid + (i << 8), r = c >> 8, o = (c & 255) << 1;
            v[i] = ald64(hb + (size_t)r * H_ + o);
          }
        }
        if (all) break;
        POLL_BACKOFF(it);
        ++it;
      }
#pragma unroll
      for (int i = 0; i < 16; ++i) {
        int c = tid + (i << 8), r = c >> 8, o = (c & 255) << 1;
        unsigned int w0 = (unsigned int)v[i];
        unsigned int w1 = (unsigned int)(v[i] >> 32);
        *(unsigned int*)&hl[r * LPAD + o] = (w0 & 0xffffu) | (w1 << 16);
      }
      __syncthreads();
      const int mm  = lane & 15;
      const int sub = lane >> 4;
#pragma unroll
      for (int cc = 0; cc < 2; ++cc) {
        const int c = ju * 2 + cc;
        const unsigned short* hrow = &hl[mm * LPAD + sub * 128];
        const float* wrow = fc_w + (size_t)c * H_ + sub * 128;
        float acc = 0.f;
#pragma unroll
        for (int kk = 0; kk < 128; kk += 8) {
          short8 hv = *(const short8*)(hrow + kk);
#pragma unroll
          for (int e = 0; e < 8; ++e)
            acc = fmaf(bf2f((unsigned short)hv[e]), wrow[kk + e], acc);
        }
        acc += __shfl_xor(acc, 16, 64);
        acc += __shfl_xor(acc, 32, 64);
        if (sub == 0) {
          float val = acc + fc_b[c];
          out[((size_t)(rowbase + mm) * HZ + p) * I_ + c] = val;   // fp32
          ast32(&xext[((size_t)p * B_ + rowbase + mm) * I_ + c],
                (((unsigned int)(p + 1)) << 16) | (unsigned int)f2bf(val));
        }
      }
      __syncthreads();   // fc reads done before next pass restages LDS[s&1]
    }
  }
}

extern "C" void kernel_launch(void* const* d_in, const int* in_sizes, int n_in,
                              void* d_out, int out_size, void* d_ws, size_t ws_size,
                              hipStream_t stream) {
  const float* x    = (const float*)d_in[0];
  const float* w_ih = (const float*)d_in[1];
  const float* w_hh = (const float*)d_in[2];
  const float* b_ih = (const float*)d_in[3];
  const float* b_hh = (const float*)d_in[4];
  const float* fc_w = (const float*)d_in[5];
  const float* fc_b = (const float*)d_in[6];
  float* out = (float*)d_out;

  unsigned char* ws = (unsigned char*)d_ws;
  const size_t hbuf_b = (size_t)2 * B_ * H_ * 4;   // 1 MiB (tagged u32)
  const size_t xext_b = (size_t)HZ * B_ * I_ * 4;  // 512 KiB (tagged u32)
  unsigned int* hbuf = (unsigned int*)ws;
  unsigned int* xext = (unsigned int*)(ws + hbuf_b);

  // zero tags (0 = invalid; the harness's 0xAA poison is also invalid)
  hipMemsetAsync(d_ws, 0, hbuf_b + xext_b, stream);

  // 128 blocks on 256 CUs — all co-resident (self-sync safe)
  gru_chain<<<dim3(128), dim3(256), 0, stream>>>(
      x, w_ih, w_hh, b_ih, b_hh, fc_w, fc_b, out, hbuf, xext);
}